// Round 1
// baseline (580.413 us; speedup 1.0000x reference)
//
#include <hip/hip_runtime.h>

// ---------------------------------------------------------------------------
// MultiHeadAttention: B=4 S=2048 MODEL=1024 H=16 Dk=Dv=64, causal.
// Pipeline: cast(QKV f32->bf16) ; transpose weights ->bf16 n-major ;
//   3x proj GEMM (8192x1024x1024, bf16 MFMA) -> q,k,vT ; flash causal attn ;
//   out GEMM (+bias, f32 out).
// Mask input (d_in[3]) is statically causal -> implemented arithmetically.
// All LDS tiles: rows of 128B, XOR swizzle byte^=((row&7)<<4), staged with
// global_load_lds(16B) from pre-swizzled global addresses (rule #21: swizzle
// source + read, linear LDS dest).
// ---------------------------------------------------------------------------

typedef __bf16 bf16;
typedef __attribute__((ext_vector_type(8))) __bf16 bf16x8;
typedef __attribute__((ext_vector_type(4))) __bf16 bf16x4;
typedef __attribute__((ext_vector_type(4))) float f32x4;
typedef unsigned int u32;

#define GLB_AS __attribute__((address_space(1)))
#define LDS_AS __attribute__((address_space(3)))

#define L2E 1.44269504088896340736f

// Stage a [rows][64 bf16] tile (row0/col0 element offsets, ldelem elements per
// global row) into LDS with XOR swizzle. 4 waves cooperate; rows*128 bytes.
static __device__ __forceinline__ void stage_swz(const bf16* __restrict__ g, long ldelem,
                                                 long row0, long col0,
                                                 bf16* lds, int rows, int tid)
{
    const int lane = tid & 63;
    const int wave = tid >> 6;
    const int nch = rows >> 3;                       // 1KB chunks
    for (int c = wave; c < nch; c += 4) {
        unsigned o  = ((unsigned)c << 10) + ((unsigned)lane << 4); // linear byte in tile
        unsigned r  = o >> 7;                         // tile row (128B/row)
        unsigned cb = o & 127u;                       // byte within row
        unsigned cs = cb ^ ((r & 7u) << 4);           // pre-swizzled source byte
        const bf16* src = g + (row0 + (long)r) * ldelem + col0 + (long)(cs >> 1);
        char* dst = (char*)lds + ((unsigned)c << 10); // wave-uniform, linear
        __builtin_amdgcn_global_load_lds((GLB_AS u32*)src, (LDS_AS u32*)dst, 16, 0, 0);
    }
}

// ---------------------------------------------------------------------------
// Prep kernels
// ---------------------------------------------------------------------------
__global__ void cast3(const float4* __restrict__ a, const float4* __restrict__ b,
                      const float4* __restrict__ c,
                      bf16x4* __restrict__ xa, bf16x4* __restrict__ xb,
                      bf16x4* __restrict__ xc)
{
    const int n4 = (8192 * 1024) / 4;
    for (int i = blockIdx.x * blockDim.x + threadIdx.x; i < n4; i += gridDim.x * blockDim.x) {
        float4 v;
        v = a[i]; xa[i] = (bf16x4){(bf16)v.x, (bf16)v.y, (bf16)v.z, (bf16)v.w};
        v = b[i]; xb[i] = (bf16x4){(bf16)v.x, (bf16)v.y, (bf16)v.z, (bf16)v.w};
        v = c[i]; xc[i] = (bf16x4){(bf16)v.x, (bf16)v.y, (bf16)v.z, (bf16)v.w};
    }
}

// Wq/Wk/Wv [16][1024][64] -> WT[(h*64+d)][1024] bf16 ; Wo [1024][1024] -> WoT[n][f]
__global__ void transw3(const float* __restrict__ wq, const float* __restrict__ wk,
                        const float* __restrict__ wv, const float* __restrict__ wo,
                        bf16* __restrict__ wqT, bf16* __restrict__ wkT,
                        bf16* __restrict__ wvT, bf16* __restrict__ woT)
{
    const int n = 16 * 1024 * 64;
    for (int i = blockIdx.x * blockDim.x + threadIdx.x; i < n; i += gridDim.x * blockDim.x) {
        int h = i >> 16, m = (i >> 6) & 1023, d = i & 63;
        long t = ((long)((h << 6) + d) << 10) + m;
        wqT[t] = (bf16)wq[i];
        wkT[t] = (bf16)wk[i];
        wvT[t] = (bf16)wv[i];
        int f = i >> 10, nn = i & 1023;
        woT[((long)nn << 10) + f] = (bf16)wo[i];
    }
}

// ---------------------------------------------------------------------------
// GEMM: C[8192][1024] = A[8192][1024] * Bt[1024][1024]^T  (Bt is n-major)
// MODE 0: bf16 out, layout [b][h][s][64]   (q / k)
// MODE 1: bf16 out, layout [b][h][64][s]   (v transposed for attention)
// MODE 2: f32 out + bias, row-major [8192][1024]
// Tile 128x128, BK=64, 4 waves (2x2), per-wave 4x4 frags of 16x16x32 bf16 MFMA.
// ---------------------------------------------------------------------------
template<int MODE>
__global__ __launch_bounds__(256, 2) void gemm8k(const bf16* __restrict__ A,
                                                 const bf16* __restrict__ Bt,
                                                 bf16* __restrict__ Cb,
                                                 float* __restrict__ Cf,
                                                 const float* __restrict__ bias)
{
    __shared__ alignas(16) bf16 sA[128 * 64];
    __shared__ alignas(16) bf16 sB[128 * 64];
    const int tid = threadIdx.x, lane = tid & 63, wave = tid >> 6;
    const int wr = wave >> 1, wc = wave & 1;
    const long row0 = (long)blockIdx.x << 7;
    const long col0 = (long)blockIdx.y << 7;

    f32x4 acc[4][4];
#pragma unroll
    for (int i = 0; i < 4; ++i)
#pragma unroll
        for (int j = 0; j < 4; ++j) acc[i][j] = (f32x4){0.f, 0.f, 0.f, 0.f};

    for (int kt = 0; kt < 16; ++kt) {
        __syncthreads();
        stage_swz(A,  1024, row0, (long)kt << 6, sA, 128, tid);
        stage_swz(Bt, 1024, col0, (long)kt << 6, sB, 128, tid);
        __syncthreads();
#pragma unroll
        for (int kk = 0; kk < 2; ++kk) {
            bf16x8 af[4], bfr[4];
            const unsigned kb = (unsigned)(kk << 6) + (unsigned)((lane >> 4) << 4);
#pragma unroll
            for (int i = 0; i < 4; ++i) {
                unsigned r = (unsigned)((wr << 6) + (i << 4) + (lane & 15));
                af[i] = *(const bf16x8*)((const char*)sA + (r << 7) + (kb ^ ((r & 7u) << 4)));
            }
#pragma unroll
            for (int j = 0; j < 4; ++j) {
                unsigned r = (unsigned)((wc << 6) + (j << 4) + (lane & 15));
                bfr[j] = *(const bf16x8*)((const char*)sB + (r << 7) + (kb ^ ((r & 7u) << 4)));
            }
#pragma unroll
            for (int i = 0; i < 4; ++i)
#pragma unroll
                for (int j = 0; j < 4; ++j)
                    acc[i][j] = __builtin_amdgcn_mfma_f32_16x16x32_bf16(af[i], bfr[j], acc[i][j], 0, 0, 0);
        }
    }

#pragma unroll
    for (int i = 0; i < 4; ++i) {
#pragma unroll
        for (int j = 0; j < 4; ++j) {
#pragma unroll
            for (int rr = 0; rr < 4; ++rr) {
                long row = row0 + (wr << 6) + (i << 4) + ((lane >> 4) << 2) + rr;
                long col = col0 + (wc << 6) + (j << 4) + (lane & 15);
                float v = acc[i][j][rr];
                if constexpr (MODE == 2) {
                    Cf[row * 1024 + col] = v + bias[col];
                } else if constexpr (MODE == 0) {
                    long idx = (((row >> 11) << 4) + (col >> 6)) * 131072 + (row & 2047) * 64 + (col & 63);
                    Cb[idx] = (bf16)v;
                } else {
                    long idx = (((row >> 11) << 4) + (col >> 6)) * 131072 + (col & 63) * 2048 + (row & 2047);
                    Cb[idx] = (bf16)v;
                }
            }
        }
    }
}

// ---------------------------------------------------------------------------
// Flash causal attention. Grid (qt=16, h=16, b=4). Block = 4 waves.
// Wave w owns 32 q rows (qt*128 + w*32); KV tiles of 64 staged block-wide.
// scale folded as score*0.125 ; softmax via exp2f(x*log2e).
// ---------------------------------------------------------------------------
__global__ __launch_bounds__(256, 2) void attn(const bf16* __restrict__ q,
                                               const bf16* __restrict__ k,
                                               const bf16* __restrict__ vT,
                                               bf16* __restrict__ o)
{
    __shared__ alignas(16) bf16 sK[64 * 64];
    __shared__ alignas(16) bf16 sV[64 * 64];
    __shared__ alignas(16) bf16 sP[4][32 * 72];     // per-wave, stride 72 (+8 pad)
    const int tid = threadIdx.x, lane = tid & 63, wave = tid >> 6;
    const int qt = blockIdx.x, h = blockIdx.y, b = blockIdx.z;
    const long hb = (long)(b * 16 + h);
    const bf16* qh = q  + hb * 131072;              // [2048][64]
    const bf16* kh = k  + hb * 131072;              // [2048][64]
    const bf16* vh = vT + hb * 131072;              // [64][2048]
    const int qw = (qt << 7) + (wave << 5);         // wave's first q row

    // Q fragments held in registers for the whole block
    bf16x8 aq[2][2];
#pragma unroll
    for (int mf = 0; mf < 2; ++mf)
#pragma unroll
        for (int kk = 0; kk < 2; ++kk)
            aq[mf][kk] = *(const bf16x8*)(qh + (long)(qw + (mf << 4) + (lane & 15)) * 64
                                             + (kk << 5) + ((lane >> 4) << 3));

    f32x4 accO[2][4];
    float mrow[2][4], lrow[2][4];
#pragma unroll
    for (int mf = 0; mf < 2; ++mf) {
#pragma unroll
        for (int nf = 0; nf < 4; ++nf) accO[mf][nf] = (f32x4){0.f, 0.f, 0.f, 0.f};
#pragma unroll
        for (int rr = 0; rr < 4; ++rr) { mrow[mf][rr] = -1e30f; lrow[mf][rr] = 0.f; }
    }

    const int nkv = (qt << 1) + 2;
    for (int kvt = 0; kvt < nkv; ++kvt) {
        const int kv0 = kvt << 6;
        __syncthreads();                            // protect prev-iter LDS reads
        stage_swz(kh, 64,   kv0, 0,   sK, 64, tid);
        stage_swz(vh, 2048, 0,   kv0, sV, 64, tid);
        __syncthreads();                            // vmcnt drain -> tiles ready

        // S = Q K^T (B-operand = K row-major = (K^T)^T, read n-major)
        f32x4 s[2][4];
#pragma unroll
        for (int mf = 0; mf < 2; ++mf)
#pragma unroll
            for (int nf = 0; nf < 4; ++nf) s[mf][nf] = (f32x4){0.f, 0.f, 0.f, 0.f};
#pragma unroll
        for (int kk = 0; kk < 2; ++kk) {
            bf16x8 bk[4];
            const unsigned kb = (unsigned)(kk << 6) + (unsigned)((lane >> 4) << 4);
#pragma unroll
            for (int nf = 0; nf < 4; ++nf) {
                unsigned r = (unsigned)((nf << 4) + (lane & 15));
                bk[nf] = *(const bf16x8*)((const char*)sK + (r << 7) + (kb ^ ((r & 7u) << 4)));
            }
#pragma unroll
            for (int mf = 0; mf < 2; ++mf)
#pragma unroll
                for (int nf = 0; nf < 4; ++nf)
                    s[mf][nf] = __builtin_amdgcn_mfma_f32_16x16x32_bf16(aq[mf][kk], bk[nf], s[mf][nf], 0, 0, 0);
        }

        // scale + causal mask + online softmax (row = qw + mf*16 + (lane>>4)*4 + rr)
        const bool domask = (kv0 + 63 > qw);
#pragma unroll
        for (int mf = 0; mf < 2; ++mf) {
#pragma unroll
            for (int rr = 0; rr < 4; ++rr) {
                const int ra = qw + (mf << 4) + ((lane >> 4) << 2) + rr;
#pragma unroll
                for (int nf = 0; nf < 4; ++nf) {
                    float v = s[mf][nf][rr] * 0.125f;
                    if (domask && (kv0 + (nf << 4) + (lane & 15)) > ra) v = -1e30f;
                    s[mf][nf][rr] = v;
                }
                float mt = fmaxf(fmaxf(s[mf][0][rr], s[mf][1][rr]), fmaxf(s[mf][2][rr], s[mf][3][rr]));
                mt = fmaxf(mt, __shfl_xor(mt, 1));
                mt = fmaxf(mt, __shfl_xor(mt, 2));
                mt = fmaxf(mt, __shfl_xor(mt, 4));
                mt = fmaxf(mt, __shfl_xor(mt, 8));
                const float mold = mrow[mf][rr];
                const float mnew = fmaxf(mold, mt);
                const float cf = __builtin_exp2f((mold - mnew) * L2E);
                mrow[mf][rr] = mnew;
                float rs = 0.f;
#pragma unroll
                for (int nf = 0; nf < 4; ++nf) {
                    float p = __builtin_exp2f((s[mf][nf][rr] - mnew) * L2E);
                    s[mf][nf][rr] = p;
                    rs += p;
                }
                rs += __shfl_xor(rs, 1);
                rs += __shfl_xor(rs, 2);
                rs += __shfl_xor(rs, 4);
                rs += __shfl_xor(rs, 8);
                lrow[mf][rr] = lrow[mf][rr] * cf + rs;
#pragma unroll
                for (int nf = 0; nf < 4; ++nf) accO[mf][nf][rr] *= cf;
            }
        }

        // P -> per-wave LDS (C-layout scatter), then PV
        bf16* pw = &sP[wave][0];
#pragma unroll
        for (int mf = 0; mf < 2; ++mf)
#pragma unroll
            for (int nf = 0; nf < 4; ++nf)
#pragma unroll
                for (int rr = 0; rr < 4; ++rr)
                    pw[((mf << 4) + ((lane >> 4) << 2) + rr) * 72 + (nf << 4) + (lane & 15)] =
                        (bf16)s[mf][nf][rr];

#pragma unroll
        for (int kk = 0; kk < 2; ++kk) {
            bf16x8 pa[2], bv[4];
#pragma unroll
            for (int mf = 0; mf < 2; ++mf)
                pa[mf] = *(const bf16x8*)(pw + ((mf << 4) + (lane & 15)) * 72
                                             + (kk << 5) + ((lane >> 4) << 3));
            const unsigned kb = (unsigned)(kk << 6) + (unsigned)((lane >> 4) << 4);
#pragma unroll
            for (int nf = 0; nf < 4; ++nf) {
                unsigned r = (unsigned)((nf << 4) + (lane & 15));
                bv[nf] = *(const bf16x8*)((const char*)sV + (r << 7) + (kb ^ ((r & 7u) << 4)));
            }
#pragma unroll
            for (int mf = 0; mf < 2; ++mf)
#pragma unroll
                for (int nf = 0; nf < 4; ++nf)
                    accO[mf][nf] = __builtin_amdgcn_mfma_f32_16x16x32_bf16(pa[mf], bv[nf], accO[mf][nf], 0, 0, 0);
        }
    }

    // O /= l ; write [b][s][h*64+d] bf16
#pragma unroll
    for (int mf = 0; mf < 2; ++mf)
#pragma unroll
        for (int rr = 0; rr < 4; ++rr) {
            const float inv = 1.f / lrow[mf][rr];
            const long ra = qw + (mf << 4) + ((lane >> 4) << 2) + rr;
#pragma unroll
            for (int nf = 0; nf < 4; ++nf)
                o[((long)b * 2048 + ra) * 1024 + (h << 6) + (nf << 4) + (lane & 15)] =
                    (bf16)(accO[mf][nf][rr] * inv);
        }
}

// ---------------------------------------------------------------------------
extern "C" void kernel_launch(void* const* d_in, const int* in_sizes, int n_in,
                              void* d_out, int out_size, void* d_ws, size_t ws_size,
                              hipStream_t stream)
{
    const float* queries = (const float*)d_in[0];
    const float* keys    = (const float*)d_in[1];
    const float* values  = (const float*)d_in[2];
    // d_in[3] = masks: statically causal, unused
    const float* Wq = (const float*)d_in[4];
    const float* Wk = (const float*)d_in[5];
    const float* Wv = (const float*)d_in[6];
    const float* Wo = (const float*)d_in[7];
    const float* bo = (const float*)d_in[8];
    float* out = (float*)d_out;

    // Workspace layout (bf16 elements). Peak = 92.3 MB with aliasing:
    //   vTp aliases Xq (free after q-proj), ao aliases Xk (free after k-proj).
    bf16* Xq  = (bf16*)d_ws;          // 8192*1024
    bf16* Xk  = Xq  + 8388608;
    bf16* Xv  = Xk  + 8388608;
    bf16* WqT = Xv  + 8388608;        // 1024*1024 each
    bf16* WkT = WqT + 1048576;
    bf16* WvT = WkT + 1048576;
    bf16* WoT = WvT + 1048576;
    bf16* qp  = WoT + 1048576;        // [4][16][2048][64]
    bf16* kp  = qp  + 8388608;
    bf16* vTp = Xq;                   // [4][16][64][2048]  (alias)
    bf16* ao  = Xk;                   // [8192][1024]       (alias)
    if (ws_size < (size_t)(2 * 8388608 + 4 * 1048576 + 2 * 8388608) * 2 + 2 * 8388608) return;

    cast3<<<dim3(2048), dim3(256), 0, stream>>>((const float4*)queries, (const float4*)keys,
                                                (const float4*)values,
                                                (bf16x4*)Xq, (bf16x4*)Xk, (bf16x4*)Xv);
    transw3<<<dim3(1024), dim3(256), 0, stream>>>(Wq, Wk, Wv, Wo, WqT, WkT, WvT, WoT);
    gemm8k<0><<<dim3(64, 8), dim3(256), 0, stream>>>(Xq, WqT, qp,  nullptr, nullptr);
    gemm8k<0><<<dim3(64, 8), dim3(256), 0, stream>>>(Xk, WkT, kp,  nullptr, nullptr);
    gemm8k<1><<<dim3(64, 8), dim3(256), 0, stream>>>(Xv, WvT, vTp, nullptr, nullptr);
    attn<<<dim3(16, 16, 4), dim3(256), 0, stream>>>(qp, kp, vTp, ao);
    gemm8k<2><<<dim3(64, 8), dim3(256), 0, stream>>>(ao, WoT, nullptr, out, bo);
}

// Round 2
// 450.585 us; speedup vs baseline: 1.2881x; 1.2881x over previous
//
#include <hip/hip_runtime.h>

// ---------------------------------------------------------------------------
// MultiHeadAttention: B=4 S=2048 MODEL=1024 H=16 Dk=Dv=64, causal.
// Pipeline: cast(QKV f32->bf16) ; transpose weights ->bf16 n-major (Wq scaled
//   by 1/sqrt(KEY)) ; 3x proj GEMM (8192x1024x1024, bf16 MFMA) -> q,k,vT ;
//   flash causal attn (qt-paired balance + double-buffered KV) ;
//   out GEMM (+bias, f32 out).
// Mask input (d_in[3]) is statically causal -> implemented arithmetically.
// All LDS tiles: rows of 128B, XOR swizzle byte^=((row&7)<<4), staged with
// global_load_lds(16B) from pre-swizzled global addresses (rule #21).
// ---------------------------------------------------------------------------

typedef __bf16 bf16;
typedef __attribute__((ext_vector_type(8))) __bf16 bf16x8;
typedef __attribute__((ext_vector_type(4))) __bf16 bf16x4;
typedef __attribute__((ext_vector_type(4))) float f32x4;
typedef unsigned int u32;

#define GLB_AS __attribute__((address_space(1)))
#define LDS_AS __attribute__((address_space(3)))

#define L2E 1.44269504088896340736f

static __device__ __forceinline__ void stage_swz(const bf16* __restrict__ g, long ldelem,
                                                 long row0, long col0,
                                                 bf16* lds, int rows, int tid)
{
    const int lane = tid & 63;
    const int wave = tid >> 6;
    const int nch = rows >> 3;                       // 1KB chunks
    for (int c = wave; c < nch; c += 4) {
        unsigned o  = ((unsigned)c << 10) + ((unsigned)lane << 4); // linear byte in tile
        unsigned r  = o >> 7;                         // tile row (128B/row)
        unsigned cb = o & 127u;                       // byte within row
        unsigned cs = cb ^ ((r & 7u) << 4);           // pre-swizzled source byte
        const bf16* src = g + (row0 + (long)r) * ldelem + col0 + (long)(cs >> 1);
        char* dst = (char*)lds + ((unsigned)c << 10); // wave-uniform, linear
        __builtin_amdgcn_global_load_lds((GLB_AS u32*)src, (LDS_AS u32*)dst, 16, 0, 0);
    }
}

// ---------------------------------------------------------------------------
// Prep kernels
// ---------------------------------------------------------------------------
__global__ void cast3(const float4* __restrict__ a, const float4* __restrict__ b,
                      const float4* __restrict__ c,
                      bf16x4* __restrict__ xa, bf16x4* __restrict__ xb,
                      bf16x4* __restrict__ xc)
{
    const int n4 = (8192 * 1024) / 4;
    for (int i = blockIdx.x * blockDim.x + threadIdx.x; i < n4; i += gridDim.x * blockDim.x) {
        float4 v;
        v = a[i]; xa[i] = (bf16x4){(bf16)v.x, (bf16)v.y, (bf16)v.z, (bf16)v.w};
        v = b[i]; xb[i] = (bf16x4){(bf16)v.x, (bf16)v.y, (bf16)v.z, (bf16)v.w};
        v = c[i]; xc[i] = (bf16x4){(bf16)v.x, (bf16)v.y, (bf16)v.z, (bf16)v.w};
    }
}

// Wq/Wk/Wv [16][1024][64] -> WT[(h*64+d)][1024] bf16 ; Wo [1024][1024] -> WoT[n][f]
// Wq is pre-scaled by 1/sqrt(KEY)=0.125 so attn needs no score scaling.
__global__ void transw3(const float* __restrict__ wq, const float* __restrict__ wk,
                        const float* __restrict__ wv, const float* __restrict__ wo,
                        bf16* __restrict__ wqT, bf16* __restrict__ wkT,
                        bf16* __restrict__ wvT, bf16* __restrict__ woT)
{
    const int n = 16 * 1024 * 64;
    for (int i = blockIdx.x * blockDim.x + threadIdx.x; i < n; i += gridDim.x * blockDim.x) {
        int h = i >> 16, m = (i >> 6) & 1023, d = i & 63;
        long t = ((long)((h << 6) + d) << 10) + m;
        wqT[t] = (bf16)(wq[i] * 0.125f);
        wkT[t] = (bf16)wk[i];
        wvT[t] = (bf16)wv[i];
        int f = i >> 10, nn = i & 1023;
        woT[((long)nn << 10) + f] = (bf16)wo[i];
    }
}

// ---------------------------------------------------------------------------
// GEMM: C[8192][1024] = A[8192][1024] * Bt[1024][1024]^T  (Bt is n-major)
// MODE 0: bf16 out, layout [b][h][s][64]   (q / k)
// MODE 1: bf16 out, layout [b][h][64][s]   (v transposed for attention)
// MODE 2: f32 out + bias, row-major [8192][1024]
// ---------------------------------------------------------------------------
template<int MODE>
__global__ __launch_bounds__(256, 2) void gemm8k(const bf16* __restrict__ A,
                                                 const bf16* __restrict__ Bt,
                                                 bf16* __restrict__ Cb,
                                                 float* __restrict__ Cf,
                                                 const float* __restrict__ bias)
{
    __shared__ alignas(16) bf16 sA[128 * 64];
    __shared__ alignas(16) bf16 sB[128 * 64];
    const int tid = threadIdx.x, lane = tid & 63, wave = tid >> 6;
    const int wr = wave >> 1, wc = wave & 1;
    const long row0 = (long)blockIdx.x << 7;
    const long col0 = (long)blockIdx.y << 7;

    f32x4 acc[4][4];
#pragma unroll
    for (int i = 0; i < 4; ++i)
#pragma unroll
        for (int j = 0; j < 4; ++j) acc[i][j] = (f32x4){0.f, 0.f, 0.f, 0.f};

    for (int kt = 0; kt < 16; ++kt) {
        __syncthreads();
        stage_swz(A,  1024, row0, (long)kt << 6, sA, 128, tid);
        stage_swz(Bt, 1024, col0, (long)kt << 6, sB, 128, tid);
        __syncthreads();
#pragma unroll
        for (int kk = 0; kk < 2; ++kk) {
            bf16x8 af[4], bfr[4];
            const unsigned kb = (unsigned)(kk << 6) + (unsigned)((lane >> 4) << 4);
#pragma unroll
            for (int i = 0; i < 4; ++i) {
                unsigned r = (unsigned)((wr << 6) + (i << 4) + (lane & 15));
                af[i] = *(const bf16x8*)((const char*)sA + (r << 7) + (kb ^ ((r & 7u) << 4)));
            }
#pragma unroll
            for (int j = 0; j < 4; ++j) {
                unsigned r = (unsigned)((wc << 6) + (j << 4) + (lane & 15));
                bfr[j] = *(const bf16x8*)((const char*)sB + (r << 7) + (kb ^ ((r & 7u) << 4)));
            }
#pragma unroll
            for (int i = 0; i < 4; ++i)
#pragma unroll
                for (int j = 0; j < 4; ++j)
                    acc[i][j] = __builtin_amdgcn_mfma_f32_16x16x32_bf16(af[i], bfr[j], acc[i][j], 0, 0, 0);
        }
    }

#pragma unroll
    for (int i = 0; i < 4; ++i) {
#pragma unroll
        for (int j = 0; j < 4; ++j) {
#pragma unroll
            for (int rr = 0; rr < 4; ++rr) {
                long row = row0 + (wr << 6) + (i << 4) + ((lane >> 4) << 2) + rr;
                long col = col0 + (wc << 6) + (j << 4) + (lane & 15);
                float v = acc[i][j][rr];
                if constexpr (MODE == 2) {
                    Cf[row * 1024 + col] = v + bias[col];
                } else if constexpr (MODE == 0) {
                    long idx = (((row >> 11) << 4) + (col >> 6)) * 131072 + (row & 2047) * 64 + (col & 63);
                    Cb[idx] = (bf16)v;
                } else {
                    long idx = (((row >> 11) << 4) + (col >> 6)) * 131072 + (col & 63) * 2048 + (row & 2047);
                    Cb[idx] = (bf16)v;
                }
            }
        }
    }
}

// ---------------------------------------------------------------------------
// Flash causal attention, balanced + double-buffered.
// Grid (8, 16, 4); block = 4 waves. Each block processes TWO q-strips of 128
// rows: qt = blockIdx.x and 15-blockIdx.x  ->  every block = 34 KV tiles.
// Per strip: 2-phase pipeline -- one __syncthreads per tile (its implicit
// vmcnt(0) drain IS the wait for the prefetch issued last iteration).
// Wq pre-scaled; causal mask arithmetic; rescale skipped when max unchanged.
// ---------------------------------------------------------------------------
__global__ __launch_bounds__(256, 2) void attn(const bf16* __restrict__ q,
                                               const bf16* __restrict__ k,
                                               const bf16* __restrict__ vT,
                                               bf16* __restrict__ o)
{
    __shared__ alignas(16) bf16 sK[2][64 * 64];
    __shared__ alignas(16) bf16 sV[2][64 * 64];
    __shared__ alignas(16) bf16 sP[4][32 * 72];     // per-wave, stride 72 (+8 pad)
    const int tid = threadIdx.x, lane = tid & 63, wave = tid >> 6;
    const int h = blockIdx.y, b = blockIdx.z;
    const long hb = (long)(b * 16 + h);
    const bf16* qh = q  + hb * 131072;              // [2048][64]
    const bf16* kh = k  + hb * 131072;              // [2048][64]
    const bf16* vh = vT + hb * 131072;              // [64][2048]

    for (int half = 0; half < 2; ++half) {
        const int qt = half ? (15 - (int)blockIdx.x) : (int)blockIdx.x;
        const int qw = (qt << 7) + (wave << 5);     // wave's first q row

        bf16x8 aq[2][2];
#pragma unroll
        for (int mf = 0; mf < 2; ++mf)
#pragma unroll
            for (int kk = 0; kk < 2; ++kk)
                aq[mf][kk] = *(const bf16x8*)(qh + (long)(qw + (mf << 4) + (lane & 15)) * 64
                                                 + (kk << 5) + ((lane >> 4) << 3));

        f32x4 accO[2][4];
        float mrow[2][4], lrow[2][4];
#pragma unroll
        for (int mf = 0; mf < 2; ++mf) {
#pragma unroll
            for (int nf = 0; nf < 4; ++nf) accO[mf][nf] = (f32x4){0.f, 0.f, 0.f, 0.f};
#pragma unroll
            for (int rr = 0; rr < 4; ++rr) { mrow[mf][rr] = -1e30f; lrow[mf][rr] = 0.f; }
        }

        const int nkv = (qt << 1) + 2;
        __syncthreads();                            // prev strip's readers done
        stage_swz(kh, 64,   0, 0, sK[0], 64, tid);
        stage_swz(vh, 2048, 0, 0, sV[0], 64, tid);

        for (int kvt = 0; kvt < nkv; ++kvt) {
            const int cur = kvt & 1;
            const int kv0 = kvt << 6;
            __syncthreads();                        // vmcnt drain -> sK/sV[cur] ready
            if (kvt + 1 < nkv) {                    // prefetch next tile into [cur^1]
                stage_swz(kh, 64,   (long)(kv0 + 64), 0, sK[cur ^ 1], 64, tid);
                stage_swz(vh, 2048, 0, (long)(kv0 + 64), sV[cur ^ 1], 64, tid);
            }
            if (kv0 > qw + 31) continue;            // fully masked for this wave

            // S = Q K^T
            f32x4 s[2][4];
#pragma unroll
            for (int mf = 0; mf < 2; ++mf)
#pragma unroll
                for (int nf = 0; nf < 4; ++nf) s[mf][nf] = (f32x4){0.f, 0.f, 0.f, 0.f};
#pragma unroll
            for (int kk = 0; kk < 2; ++kk) {
                bf16x8 bk[4];
                const unsigned kb = (unsigned)(kk << 6) + (unsigned)((lane >> 4) << 4);
#pragma unroll
                for (int nf = 0; nf < 4; ++nf) {
                    unsigned r = (unsigned)((nf << 4) + (lane & 15));
                    bk[nf] = *(const bf16x8*)((const char*)sK[cur] + (r << 7) + (kb ^ ((r & 7u) << 4)));
                }
#pragma unroll
                for (int mf = 0; mf < 2; ++mf)
#pragma unroll
                    for (int nf = 0; nf < 4; ++nf)
                        s[mf][nf] = __builtin_amdgcn_mfma_f32_16x16x32_bf16(aq[mf][kk], bk[nf], s[mf][nf], 0, 0, 0);
            }

            // causal mask (only diagonal tiles)
            if (kv0 + 63 > qw) {
#pragma unroll
                for (int mf = 0; mf < 2; ++mf)
#pragma unroll
                    for (int rr = 0; rr < 4; ++rr) {
                        const int ra = qw + (mf << 4) + ((lane >> 4) << 2) + rr;
#pragma unroll
                        for (int nf = 0; nf < 4; ++nf)
                            if ((kv0 + (nf << 4) + (lane & 15)) > ra) s[mf][nf][rr] = -1e30f;
                    }
            }

            // online softmax; rescale only when the row max grew
#pragma unroll
            for (int mf = 0; mf < 2; ++mf) {
#pragma unroll
                for (int rr = 0; rr < 4; ++rr) {
                    float mt = fmaxf(fmaxf(s[mf][0][rr], s[mf][1][rr]), fmaxf(s[mf][2][rr], s[mf][3][rr]));
                    mt = fmaxf(mt, __shfl_xor(mt, 1));
                    mt = fmaxf(mt, __shfl_xor(mt, 2));
                    mt = fmaxf(mt, __shfl_xor(mt, 4));
                    mt = fmaxf(mt, __shfl_xor(mt, 8));
                    if (mt > mrow[mf][rr]) {        // uniform per 16-lane group
                        const float cf = __builtin_exp2f((mrow[mf][rr] - mt) * L2E);
                        mrow[mf][rr] = mt;
                        lrow[mf][rr] *= cf;
#pragma unroll
                        for (int nf = 0; nf < 4; ++nf) accO[mf][nf][rr] *= cf;
                    }
                    const float mnew = mrow[mf][rr];
                    float rs = 0.f;
#pragma unroll
                    for (int nf = 0; nf < 4; ++nf) {
                        float p = __builtin_exp2f((s[mf][nf][rr] - mnew) * L2E);
                        s[mf][nf][rr] = p;
                        rs += p;
                    }
                    rs += __shfl_xor(rs, 1);
                    rs += __shfl_xor(rs, 2);
                    rs += __shfl_xor(rs, 4);
                    rs += __shfl_xor(rs, 8);
                    lrow[mf][rr] += rs;
                }
            }

            // P -> per-wave LDS (C-layout scatter), then PV
            bf16* pw = &sP[wave][0];
#pragma unroll
            for (int mf = 0; mf < 2; ++mf)
#pragma unroll
                for (int nf = 0; nf < 4; ++nf)
#pragma unroll
                    for (int rr = 0; rr < 4; ++rr)
                        pw[((mf << 4) + ((lane >> 4) << 2) + rr) * 72 + (nf << 4) + (lane & 15)] =
                            (bf16)s[mf][nf][rr];

#pragma unroll
            for (int kk = 0; kk < 2; ++kk) {
                bf16x8 pa[2], bv[4];
#pragma unroll
                for (int mf = 0; mf < 2; ++mf)
                    pa[mf] = *(const bf16x8*)(pw + ((mf << 4) + (lane & 15)) * 72
                                                 + (kk << 5) + ((lane >> 4) << 3));
                const unsigned kb = (unsigned)(kk << 6) + (unsigned)((lane >> 4) << 4);
#pragma unroll
                for (int nf = 0; nf < 4; ++nf) {
                    unsigned r = (unsigned)((nf << 4) + (lane & 15));
                    bv[nf] = *(const bf16x8*)((const char*)sV[cur] + (r << 7) + (kb ^ ((r & 7u) << 4)));
                }
#pragma unroll
                for (int mf = 0; mf < 2; ++mf)
#pragma unroll
                    for (int nf = 0; nf < 4; ++nf)
                        accO[mf][nf] = __builtin_amdgcn_mfma_f32_16x16x32_bf16(pa[mf], bv[nf], accO[mf][nf], 0, 0, 0);
            }
        }

        // O /= l ; write [b][s][h*64+d] bf16
#pragma unroll
        for (int mf = 0; mf < 2; ++mf)
#pragma unroll
            for (int rr = 0; rr < 4; ++rr) {
                const float inv = 1.f / lrow[mf][rr];
                const long ra = qw + (mf << 4) + ((lane >> 4) << 2) + rr;
#pragma unroll
                for (int nf = 0; nf < 4; ++nf)
                    o[((long)b * 2048 + ra) * 1024 + (h << 6) + (nf << 4) + (lane & 15)] =
                        (bf16)(accO[mf][nf][rr] * inv);
            }
    }
}

// ---------------------------------------------------------------------------
extern "C" void kernel_launch(void* const* d_in, const int* in_sizes, int n_in,
                              void* d_out, int out_size, void* d_ws, size_t ws_size,
                              hipStream_t stream)
{
    const float* queries = (const float*)d_in[0];
    const float* keys    = (const float*)d_in[1];
    const float* values  = (const float*)d_in[2];
    // d_in[3] = masks: statically causal, unused
    const float* Wq = (const float*)d_in[4];
    const float* Wk = (const float*)d_in[5];
    const float* Wv = (const float*)d_in[6];
    const float* Wo = (const float*)d_in[7];
    const float* bo = (const float*)d_in[8];
    float* out = (float*)d_out;

    bf16* Xq  = (bf16*)d_ws;          // 8192*1024
    bf16* Xk  = Xq  + 8388608;
    bf16* Xv  = Xk  + 8388608;
    bf16* WqT = Xv  + 8388608;        // 1024*1024 each
    bf16* WkT = WqT + 1048576;
    bf16* WvT = WkT + 1048576;
    bf16* WoT = WvT + 1048576;
    bf16* qp  = WoT + 1048576;        // [4][16][2048][64]
    bf16* kp  = qp  + 8388608;
    bf16* vTp = Xq;                   // [4][16][64][2048]  (alias, Xq dead after q-proj)
    bf16* ao  = Xk;                   // [8192][1024]       (alias, Xk dead after k-proj)
    if (ws_size < (size_t)92274688) return;

    cast3<<<dim3(2048), dim3(256), 0, stream>>>((const float4*)queries, (const float4*)keys,
                                                (const float4*)values,
                                                (bf16x4*)Xq, (bf16x4*)Xk, (bf16x4*)Xv);
    transw3<<<dim3(1024), dim3(256), 0, stream>>>(Wq, Wk, Wv, Wo, WqT, WkT, WvT, WoT);
    gemm8k<0><<<dim3(64, 8), dim3(256), 0, stream>>>(Xq, WqT, qp,  nullptr, nullptr);
    gemm8k<0><<<dim3(64, 8), dim3(256), 0, stream>>>(Xk, WkT, kp,  nullptr, nullptr);
    gemm8k<1><<<dim3(64, 8), dim3(256), 0, stream>>>(Xv, WvT, vTp, nullptr, nullptr);
    attn<<<dim3(8, 16, 4), dim3(256), 0, stream>>>(qp, kp, vTp, ao);
    gemm8k<2><<<dim3(64, 8), dim3(256), 0, stream>>>(ao, WoT, nullptr, out, bo);
}